// Round 2
// baseline (176.898 us; speedup 1.0000x reference)
//
#include <hip/hip_runtime.h>

// GNNModel: B=1,S=32,N=2048,F=64,H=128,E=32768.
// Key insight: reference returns out[:, -1] only -> compute timestep t=31 only.

#define N_NODES 2048
#define F_IN 64
#define H_DIM 128
#define S_LEN 32
#define E_EDGES 32768
#define T_LAST (S_LEN - 1)

__device__ __forceinline__ float lrelu(float v) { return v > 0.0f ? v : 0.01f * v; }

// Kernel 1: h2 = lrelu(lrelu(x31 @ W1 + b1) @ W2 + b2); also zero agg/cnt.
// 256 blocks x 256 threads, 8 nodes per block.
__global__ __launch_bounds__(256) void k_h2(
    const float* __restrict__ x,
    const float* __restrict__ W1, const float* __restrict__ b1,
    const float* __restrict__ W2, const float* __restrict__ b2,
    float* __restrict__ h2, float* __restrict__ agg, float* __restrict__ cnt)
{
    __shared__ float xs[8][F_IN];     // 2 KB
    __shared__ float h1s[8][H_DIM];   // 4 KB
    const int t = threadIdx.x;
    const int node0 = blockIdx.x * 8;

    // zero this block's agg rows (8*128 = 1024 floats = 256 float4) and cnt
    ((float4*)(agg + (size_t)node0 * H_DIM))[t] = make_float4(0.f, 0.f, 0.f, 0.f);
    if (t < 8) cnt[node0 + t] = 0.f;

    // load 8 x-rows (512 floats = 256 float2), t=31 slice
    {
        const float* xsrc = x + ((size_t)T_LAST * N_NODES + node0) * F_IN;
        ((float2*)&xs[0][0])[t] = ((const float2*)xsrc)[t];
    }
    __syncthreads();

    const int half = t >> 7;       // 0/1
    const int j = t & 127;         // output dim
    const int nbase = half * 4;    // 4 nodes per (half, j) thread

    // layer 1: [64 -> 128]
    float acc[4];
    {
        float bb = b1[j];
        acc[0] = bb; acc[1] = bb; acc[2] = bb; acc[3] = bb;
        for (int k = 0; k < F_IN; ++k) {
            float w = W1[k * H_DIM + j];
            #pragma unroll
            for (int m = 0; m < 4; ++m) acc[m] += xs[nbase + m][k] * w;
        }
        #pragma unroll
        for (int m = 0; m < 4; ++m) h1s[nbase + m][j] = lrelu(acc[m]);
    }
    __syncthreads();

    // layer 2: [128 -> 128]
    {
        float bb = b2[j];
        float a2[4] = {bb, bb, bb, bb};
        for (int k = 0; k < H_DIM; ++k) {
            float w = W2[k * H_DIM + j];
            #pragma unroll
            for (int m = 0; m < 4; ++m) a2[m] += h1s[nbase + m][k] * w;
        }
        #pragma unroll
        for (int m = 0; m < 4; ++m)
            h2[(size_t)(node0 + nbase + m) * H_DIM + j] = lrelu(a2[m]);
    }
}

// Kernel 2: scatter-sum over edges of t=31. 32 threads per edge (4 dims each).
__global__ __launch_bounds__(256) void k_scatter(
    const int* __restrict__ ei, const float* __restrict__ h2,
    float* __restrict__ agg, float* __restrict__ cnt)
{
    const int idx = blockIdx.x * 256 + threadIdx.x;   // E*32 total
    const int e = idx >> 5;
    const int part = idx & 31;
    const int src = ei[(size_t)T_LAST * E_EDGES + e];
    const int tgt = ei[(size_t)S_LEN * E_EDGES + (size_t)T_LAST * E_EDGES + e];
    const float4 v = ((const float4*)(h2 + (size_t)src * H_DIM))[part];
    float* dst = agg + (size_t)tgt * H_DIM + part * 4;
    atomicAdd(dst + 0, v.x);
    atomicAdd(dst + 1, v.y);
    atomicAdd(dst + 2, v.z);
    atomicAdd(dst + 3, v.w);
    if (part == 0) atomicAdd(&cnt[tgt], 1.0f);
}

// Kernel 3: gnn = lrelu(agg/cnt @ Wrel + brel + h2 @ Wroot);
//           o3 = lrelu(gnn @ W3 + b3); out = o3 @ W4 + b4.
// 256 blocks x 256 threads, 8 nodes per block.
__global__ __launch_bounds__(256) void k_final(
    const float* __restrict__ h2,
    const float* __restrict__ agg, const float* __restrict__ cnt,
    const float* __restrict__ Wrel, const float* __restrict__ brel,
    const float* __restrict__ Wroot,
    const float* __restrict__ W3, const float* __restrict__ b3,
    const float* __restrict__ W4, const float* __restrict__ b4,
    float* __restrict__ out)
{
    __shared__ float aggs[8][H_DIM];
    __shared__ float h2s[8][H_DIM];
    __shared__ float gs[8][H_DIM];
    __shared__ float ps[8][H_DIM];
    const int t = threadIdx.x;
    const int node0 = blockIdx.x * 8;

    // load agg (with mean division) and h2: 1024 floats each, 4/thread
    {
        float4 a4 = ((const float4*)(agg + (size_t)node0 * H_DIM))[t];
        const int n = t >> 5;  // row of the 4 consecutive floats
        const float inv = 1.0f / fmaxf(cnt[node0 + n], 1.0f);
        a4.x *= inv; a4.y *= inv; a4.z *= inv; a4.w *= inv;
        ((float4*)&aggs[0][0])[t] = a4;
        ((float4*)&h2s[0][0])[t] = ((const float4*)(h2 + (size_t)node0 * H_DIM))[t];
    }
    __syncthreads();

    const int half = t >> 7;
    const int j = t & 127;
    const int nbase = half * 4;

    // gnn layer: two weight streams fused
    {
        float bb = brel[j];
        float acc[4] = {bb, bb, bb, bb};
        for (int k = 0; k < H_DIM; ++k) {
            float wr = Wrel[k * H_DIM + j];
            float wo = Wroot[k * H_DIM + j];
            #pragma unroll
            for (int m = 0; m < 4; ++m)
                acc[m] += aggs[nbase + m][k] * wr + h2s[nbase + m][k] * wo;
        }
        #pragma unroll
        for (int m = 0; m < 4; ++m) gs[nbase + m][j] = lrelu(acc[m]);
    }
    __syncthreads();

    // head: o3 = lrelu(gs @ W3 + b3), then per-node dot with W4
    {
        float bb = b3[j];
        float acc[4] = {bb, bb, bb, bb};
        for (int k = 0; k < H_DIM; ++k) {
            float w = W3[k * H_DIM + j];
            #pragma unroll
            for (int m = 0; m < 4; ++m) acc[m] += gs[nbase + m][k] * w;
        }
        const float w4 = W4[j];
        #pragma unroll
        for (int m = 0; m < 4; ++m) ps[nbase + m][j] = lrelu(acc[m]) * w4;
    }
    __syncthreads();

    // tree-reduce 128 j-values per node
    for (int stride = 64; stride >= 1; stride >>= 1) {
        if (j < stride) {
            #pragma unroll
            for (int m = 0; m < 4; ++m)
                ps[nbase + m][j] += ps[nbase + m][j + stride];
        }
        __syncthreads();
    }
    if (j == 0) {
        const float bb4 = b4[0];
        #pragma unroll
        for (int m = 0; m < 4; ++m)
            out[node0 + nbase + m] = ps[nbase + m][0] + bb4;
    }
}

extern "C" void kernel_launch(void* const* d_in, const int* in_sizes, int n_in,
                              void* d_out, int out_size, void* d_ws, size_t ws_size,
                              hipStream_t stream)
{
    const float* x     = (const float*)d_in[0];
    const int*   ei    = (const int*)d_in[1];
    // d_in[2] = edgenum scalar (compile-time constant here)
    const float* W1    = (const float*)d_in[3];
    const float* b1    = (const float*)d_in[4];
    const float* W2    = (const float*)d_in[5];
    const float* b2    = (const float*)d_in[6];
    const float* Wrel  = (const float*)d_in[7];
    const float* brel  = (const float*)d_in[8];
    const float* Wroot = (const float*)d_in[9];
    const float* W3    = (const float*)d_in[10];
    const float* b3    = (const float*)d_in[11];
    const float* W4    = (const float*)d_in[12];
    const float* b4    = (const float*)d_in[13];
    float* out = (float*)d_out;

    float* h2  = (float*)d_ws;                         // 2048*128 f32
    float* agg = h2 + (size_t)N_NODES * H_DIM;         // 2048*128 f32
    float* cnt = agg + (size_t)N_NODES * H_DIM;        // 2048 f32

    k_h2<<<N_NODES / 8, 256, 0, stream>>>(x, W1, b1, W2, b2, h2, agg, cnt);
    k_scatter<<<(E_EDGES * 32) / 256, 256, 0, stream>>>(ei, h2, agg, cnt);
    k_final<<<N_NODES / 8, 256, 0, stream>>>(h2, agg, cnt, Wrel, brel, Wroot,
                                             W3, b3, W4, b4, out);
}

// Round 3
// 128.325 us; speedup vs baseline: 1.3785x; 1.3785x over previous
//
#include <hip/hip_runtime.h>

// GNNModel: B=1,S=32,N=2048,F=64,H=128,E=32768.
// Only t=31 contributes to the output -> compute last timestep only.
// R2 change: scatter (4.2M device-scope f32 atomics -> 66MB HBM writes, 63us)
// replaced by bucket-build (32K int atomics) + gather fused into k_final.

#define N_NODES 2048
#define F_IN 64
#define H_DIM 128
#define S_LEN 32
#define E_EDGES 32768
#define T_LAST (S_LEN - 1)
#define CAP 96   // max in-degree capacity; E/N=16 mean, binomial tail << 96

__device__ __forceinline__ float lrelu(float v) { return v > 0.0f ? v : 0.01f * v; }

// Kernel 1: h2 = lrelu(lrelu(x31 @ W1 + b1) @ W2 + b2); also zero deg.
// 256 blocks x 256 threads, 8 nodes per block.
__global__ __launch_bounds__(256) void k_h2(
    const float* __restrict__ x,
    const float* __restrict__ W1, const float* __restrict__ b1,
    const float* __restrict__ W2, const float* __restrict__ b2,
    float* __restrict__ h2, int* __restrict__ deg)
{
    __shared__ float xs[8][F_IN];     // 2 KB
    __shared__ float h1s[8][H_DIM];   // 4 KB
    const int t = threadIdx.x;
    const int node0 = blockIdx.x * 8;

    if (t < 8) deg[node0 + t] = 0;

    // load 8 x-rows (512 floats = 256 float2), t=31 slice
    {
        const float* xsrc = x + ((size_t)T_LAST * N_NODES + node0) * F_IN;
        ((float2*)&xs[0][0])[t] = ((const float2*)xsrc)[t];
    }
    __syncthreads();

    const int half = t >> 7;       // 0/1
    const int j = t & 127;         // output dim
    const int nbase = half * 4;    // 4 nodes per (half, j) thread

    // layer 1: [64 -> 128]
    {
        float bb = b1[j];
        float acc[4] = {bb, bb, bb, bb};
        for (int k = 0; k < F_IN; ++k) {
            float w = W1[k * H_DIM + j];
            #pragma unroll
            for (int m = 0; m < 4; ++m) acc[m] += xs[nbase + m][k] * w;
        }
        #pragma unroll
        for (int m = 0; m < 4; ++m) h1s[nbase + m][j] = lrelu(acc[m]);
    }
    __syncthreads();

    // layer 2: [128 -> 128]
    {
        float bb = b2[j];
        float a2[4] = {bb, bb, bb, bb};
        for (int k = 0; k < H_DIM; ++k) {
            float w = W2[k * H_DIM + j];
            #pragma unroll
            for (int m = 0; m < 4; ++m) a2[m] += h1s[nbase + m][k] * w;
        }
        #pragma unroll
        for (int m = 0; m < 4; ++m)
            h2[(size_t)(node0 + nbase + m) * H_DIM + j] = lrelu(a2[m]);
    }
}

// Kernel 2: bucket build. One thread per edge; 32K int atomics (vs 4.2M f32).
__global__ __launch_bounds__(256) void k_bucket(
    const int* __restrict__ ei, int* __restrict__ deg, int* __restrict__ bucket)
{
    const int e = blockIdx.x * 256 + threadIdx.x;
    const int src = ei[(size_t)T_LAST * E_EDGES + e];
    const int tgt = ei[(size_t)S_LEN * E_EDGES + (size_t)T_LAST * E_EDGES + e];
    const int slot = atomicAdd(&deg[tgt], 1);
    if (slot < CAP) bucket[tgt * CAP + slot] = src;
}

// Kernel 3: gather-mean + gnn + head. 256 blocks x 256 threads, 8 nodes/block.
__global__ __launch_bounds__(256) void k_final(
    const float* __restrict__ h2,
    const int* __restrict__ deg, const int* __restrict__ bucket,
    const float* __restrict__ Wrel, const float* __restrict__ brel,
    const float* __restrict__ Wroot,
    const float* __restrict__ W3, const float* __restrict__ b3,
    const float* __restrict__ W4, const float* __restrict__ b4,
    float* __restrict__ out)
{
    __shared__ float aggs[8][H_DIM];  // 4 KB
    __shared__ float h2s[8][H_DIM];   // 4 KB
    __shared__ float gs[8][H_DIM];    // 4 KB
    __shared__ float ps[8][H_DIM];    // 4 KB
    __shared__ int   bl[8][CAP];      // 3 KB edge lists
    __shared__ int   dgs[8];
    const int t = threadIdx.x;
    const int node0 = blockIdx.x * 8;

    // stage h2 rows of this block's 8 nodes (1024 floats = 256 float4)
    ((float4*)&h2s[0][0])[t] = ((const float4*)(h2 + (size_t)node0 * H_DIM))[t];

    // stage bucket lists: 8 groups of 32 lanes, one node each
    {
        const int nidx = t >> 5;      // 0..7
        const int lane = t & 31;
        const int n = node0 + nidx;
        const int dg = min(deg[n], CAP);
        if (lane == 0) dgs[nidx] = dg;
        for (int i = lane; i < dg; i += 32)
            bl[nidx][i] = bucket[n * CAP + i];
    }
    __syncthreads();

    const int half = t >> 7;
    const int j = t & 127;
    const int nbase = half * 4;

    // gather-mean: agg[n][j] = mean_i h2[bl[n][i]][j]
    #pragma unroll
    for (int m = 0; m < 4; ++m) {
        const int nidx = nbase + m;
        const int dg = dgs[nidx];
        float acc = 0.0f;
        for (int i = 0; i < dg; ++i) {
            const int src = bl[nidx][i];
            acc += h2[(size_t)src * H_DIM + j];
        }
        aggs[nidx][j] = acc / fmaxf((float)dg, 1.0f);
    }
    __syncthreads();

    // gnn layer: lrelu(agg @ Wrel + brel + h2 @ Wroot)
    {
        float bb = brel[j];
        float acc[4] = {bb, bb, bb, bb};
        for (int k = 0; k < H_DIM; ++k) {
            float wr = Wrel[k * H_DIM + j];
            float wo = Wroot[k * H_DIM + j];
            #pragma unroll
            for (int m = 0; m < 4; ++m)
                acc[m] += aggs[nbase + m][k] * wr + h2s[nbase + m][k] * wo;
        }
        #pragma unroll
        for (int m = 0; m < 4; ++m) gs[nbase + m][j] = lrelu(acc[m]);
    }
    __syncthreads();

    // head: o3 = lrelu(gs @ W3 + b3), then per-node dot with W4
    {
        float bb = b3[j];
        float acc[4] = {bb, bb, bb, bb};
        for (int k = 0; k < H_DIM; ++k) {
            float w = W3[k * H_DIM + j];
            #pragma unroll
            for (int m = 0; m < 4; ++m) acc[m] += gs[nbase + m][k] * w;
        }
        const float w4 = W4[j];
        #pragma unroll
        for (int m = 0; m < 4; ++m) ps[nbase + m][j] = lrelu(acc[m]) * w4;
    }
    __syncthreads();

    // tree-reduce 128 j-values per node
    for (int stride = 64; stride >= 1; stride >>= 1) {
        if (j < stride) {
            #pragma unroll
            for (int m = 0; m < 4; ++m)
                ps[nbase + m][j] += ps[nbase + m][j + stride];
        }
        __syncthreads();
    }
    if (j == 0) {
        const float bb4 = b4[0];
        #pragma unroll
        for (int m = 0; m < 4; ++m)
            out[node0 + nbase + m] = ps[nbase + m][0] + bb4;
    }
}

extern "C" void kernel_launch(void* const* d_in, const int* in_sizes, int n_in,
                              void* d_out, int out_size, void* d_ws, size_t ws_size,
                              hipStream_t stream)
{
    const float* x     = (const float*)d_in[0];
    const int*   ei    = (const int*)d_in[1];
    // d_in[2] = edgenum scalar (compile-time constant here)
    const float* W1    = (const float*)d_in[3];
    const float* b1    = (const float*)d_in[4];
    const float* W2    = (const float*)d_in[5];
    const float* b2    = (const float*)d_in[6];
    const float* Wrel  = (const float*)d_in[7];
    const float* brel  = (const float*)d_in[8];
    const float* Wroot = (const float*)d_in[9];
    const float* W3    = (const float*)d_in[10];
    const float* b3    = (const float*)d_in[11];
    const float* W4    = (const float*)d_in[12];
    const float* b4    = (const float*)d_in[13];
    float* out = (float*)d_out;

    float* h2     = (float*)d_ws;                      // 2048*128 f32 (1 MB)
    int*   deg    = (int*)(h2 + (size_t)N_NODES * H_DIM);   // 2048 i32
    int*   bucket = deg + N_NODES;                     // 2048*96 i32 (768 KB)

    k_h2<<<N_NODES / 8, 256, 0, stream>>>(x, W1, b1, W2, b2, h2, deg);
    k_bucket<<<E_EDGES / 256, 256, 0, stream>>>(ei, deg, bucket);
    k_final<<<N_NODES / 8, 256, 0, stream>>>(h2, deg, bucket, Wrel, brel, Wroot,
                                             W3, b3, W4, b4, out);
}

// Round 8
// 128.118 us; speedup vs baseline: 1.3807x; 1.0016x over previous
//
#include <hip/hip_runtime.h>

// GNNModel: B=1,S=32,N=2048,F=64,H=128,E=32768. Only t=31 matters.
// R4: single fused kernel (bucket-build ∥ h2 MLP -> grid barrier -> gather+gnn+head)
//     + hipMemsetAsync zeroing deg+barrier. Removes 2 launch gaps and the
//     latency-bound 1-wave/SIMD structure (512-thr blocks = 2 waves/SIMD).

#define N_NODES 2048
#define F_IN 64
#define H_DIM 128
#define S_LEN 32
#define E_EDGES 32768
#define T_LAST (S_LEN - 1)
#define CAP 96          // max in-degree capacity; E/N=16 mean, tail << 96
#define NBLK 256
#define TPB 512

__device__ __forceinline__ float lrelu(float v) { return v > 0.0f ? v : 0.01f * v; }

__global__ __launch_bounds__(TPB) void k_fused(
    const float* __restrict__ x, const int* __restrict__ ei,
    const float* __restrict__ W1, const float* __restrict__ b1,
    const float* __restrict__ W2, const float* __restrict__ b2,
    const float* __restrict__ Wrel, const float* __restrict__ brel,
    const float* __restrict__ Wroot,
    const float* __restrict__ W3, const float* __restrict__ b3,
    const float* __restrict__ W4, const float* __restrict__ b4,
    float* __restrict__ out,
    int* __restrict__ deg, unsigned int* __restrict__ bar,
    int* __restrict__ bucket, float* __restrict__ h2)
{
    __shared__ float xs[8][F_IN];     // 2 KB
    __shared__ float h1s[8][H_DIM];   // 4 KB
    __shared__ float aggs[8][H_DIM];  // 4 KB
    __shared__ float h2s[8][H_DIM];   // 4 KB (this block's h2, kept across barrier)
    __shared__ float gs[8][H_DIM];    // 4 KB
    __shared__ int   bl[8][CAP];      // 3 KB
    __shared__ int   dgs[8];
    __shared__ float pred[8][2];      // per-wave reduce partials

    const int t = threadIdx.x;
    const int bid = blockIdx.x;
    const int node0 = bid * 8;

    // ---- bucket build (deg pre-zeroed by memset; independent of h2) ----
    if (t < 128) {
        const int e = bid * 128 + t;
        const int src = ei[(size_t)T_LAST * E_EDGES + e];
        const int tgt = ei[(size_t)(S_LEN + T_LAST) * E_EDGES + e];
        const int slot = atomicAdd(&deg[tgt], 1);
        if (slot < CAP) bucket[tgt * CAP + slot] = src;
    }

    // ---- h2 = lrelu(lrelu(x31@W1+b1)@W2+b2), 8 nodes/block ----
    if (t < 256) {
        const float* xsrc = x + ((size_t)T_LAST * N_NODES + node0) * F_IN;
        ((float2*)&xs[0][0])[t] = ((const float2*)xsrc)[t];
    }
    __syncthreads();

    const int j = t & 127;      // output dim
    const int q = t >> 7;       // 0..3
    const int nb = q * 2;       // 2 nodes per thread

    {
        const float bb = b1[j];
        float a0 = bb, a1 = bb;
        for (int k = 0; k < F_IN; ++k) {
            const float w = W1[k * H_DIM + j];
            a0 += xs[nb][k] * w; a1 += xs[nb + 1][k] * w;
        }
        h1s[nb][j] = lrelu(a0); h1s[nb + 1][j] = lrelu(a1);
    }
    __syncthreads();
    {
        const float bb = b2[j];
        float a0 = bb, a1 = bb;
        for (int k = 0; k < H_DIM; ++k) {
            const float w = W2[k * H_DIM + j];
            a0 += h1s[nb][k] * w; a1 += h1s[nb + 1][k] * w;
        }
        a0 = lrelu(a0); a1 = lrelu(a1);
        h2[(size_t)(node0 + nb) * H_DIM + j] = a0;
        h2[(size_t)(node0 + nb + 1) * H_DIM + j] = a1;
        h2s[nb][j] = a0; h2s[nb + 1][j] = a1;   // keep own tile in LDS
    }

    // ---- grid barrier (device-scope; co-residency guaranteed by capacity) ----
    __syncthreads();
    if (t == 0) {
        __hip_atomic_fetch_add(bar, 1u, __ATOMIC_ACQ_REL, __HIP_MEMORY_SCOPE_AGENT);
        while (__hip_atomic_load(bar, __ATOMIC_ACQUIRE, __HIP_MEMORY_SCOPE_AGENT) < NBLK)
            __builtin_amdgcn_s_sleep(1);
    }
    __syncthreads();

    // ---- stage bucket lists (64 lanes per node) ----
    {
        const int g = t >> 6, lane = t & 63;
        const int n = node0 + g;
        const int dg = min(deg[n], CAP);
        if (lane == 0) dgs[g] = dg;
        for (int i = lane; i < dg; i += 64) bl[g][i] = bucket[n * CAP + i];
    }
    __syncthreads();

    // ---- gather-mean: agg[n][j] = mean_i h2[bl[n][i]][j] ----
    #pragma unroll
    for (int m = 0; m < 2; ++m) {
        const int n = nb + m;
        const int dg = dgs[n];
        float acc = 0.0f;
        for (int i = 0; i < dg; ++i)
            acc += h2[(size_t)bl[n][i] * H_DIM + j];
        aggs[n][j] = acc / fmaxf((float)dg, 1.0f);
    }
    __syncthreads();

    // ---- gnn: lrelu(agg@Wrel + brel + h2@Wroot) ----
    {
        const float bb = brel[j];
        float a0 = bb, a1 = bb;
        for (int k = 0; k < H_DIM; ++k) {
            const float wr = Wrel[k * H_DIM + j];
            const float wo = Wroot[k * H_DIM + j];
            a0 += aggs[nb][k] * wr + h2s[nb][k] * wo;
            a1 += aggs[nb + 1][k] * wr + h2s[nb + 1][k] * wo;
        }
        gs[nb][j] = lrelu(a0); gs[nb + 1][j] = lrelu(a1);
    }
    __syncthreads();

    // ---- head: lrelu(gs@W3+b3) dot W4 ----
    float p0, p1;
    {
        const float bb = b3[j];
        float a0 = bb, a1 = bb;
        for (int k = 0; k < H_DIM; ++k) {
            const float w = W3[k * H_DIM + j];
            a0 += gs[nb][k] * w; a1 += gs[nb + 1][k] * w;
        }
        const float w4 = W4[j];
        p0 = lrelu(a0) * w4; p1 = lrelu(a1) * w4;
    }
    // per-wave butterfly reduce (64 lanes), then tiny LDS combine
    for (int off = 32; off >= 1; off >>= 1) {
        p0 += __shfl_down(p0, off);
        p1 += __shfl_down(p1, off);
    }
    const int w = t >> 6;                 // wave id 0..7
    if ((t & 63) == 0) { pred[w][0] = p0; pred[w][1] = p1; }
    __syncthreads();
    if (t < 8) {
        // node n -> q=n>>1 owns waves 2q (j 0..63) and 2q+1 (j 64..127)
        const int n = t, qq = n >> 1, mm = n & 1;
        out[node0 + n] = pred[2 * qq][mm] + pred[2 * qq + 1][mm] + b4[0];
    }
}

extern "C" void kernel_launch(void* const* d_in, const int* in_sizes, int n_in,
                              void* d_out, int out_size, void* d_ws, size_t ws_size,
                              hipStream_t stream)
{
    const float* x     = (const float*)d_in[0];
    const int*   ei    = (const int*)d_in[1];
    // d_in[2] = edgenum scalar (compile-time constant here)
    const float* W1    = (const float*)d_in[3];
    const float* b1    = (const float*)d_in[4];
    const float* W2    = (const float*)d_in[5];
    const float* b2    = (const float*)d_in[6];
    const float* Wrel  = (const float*)d_in[7];
    const float* brel  = (const float*)d_in[8];
    const float* Wroot = (const float*)d_in[9];
    const float* W3    = (const float*)d_in[10];
    const float* b3    = (const float*)d_in[11];
    const float* W4    = (const float*)d_in[12];
    const float* b4    = (const float*)d_in[13];
    float* out = (float*)d_out;

    // ws layout (all i32/f32 = 4 B):
    //   [0 .. 2048)            deg
    //   [2048 .. 2064)         barrier counter (+pad)
    //   [2064 .. 198672)       bucket[2048][96]
    //   [198672 .. 460816)     h2[2048][128]
    int*      deg    = (int*)d_ws;
    unsigned* bar    = (unsigned*)((int*)d_ws + 2048);
    int*      bucket = (int*)d_ws + 2064;
    float*    h2     = (float*)((int*)d_ws + 2064 + N_NODES * CAP);

    // zero deg + barrier counter (graph-capturable stream op)
    hipMemsetAsync(d_ws, 0, (2048 + 16) * sizeof(int), stream);

    k_fused<<<NBLK, TPB, 0, stream>>>(x, ei, W1, b1, W2, b2, Wrel, brel, Wroot,
                                      W3, b3, W4, b4, out, deg, bar, bucket, h2);
}